// Round 1
// baseline (2685.678 us; speedup 1.0000x reference)
//
#include <hip/hip_runtime.h>
#include <math.h>

// Flow log_prob, fp32 end-to-end.
// Pipeline per level i (s=12<<i, d=s/2, h=128>>i, Cfull=12<<2i, nvec=8*h*h):
//   s2d -> expm_apply (Taylor of expm(-M) applied to (y-eb) in-kernel) ->
//   fused conv3x3(d->256)+relu+dense(256->d) writing [x0, x1-shift] back.
// Then per-batch sum(z^2) + ildj from traces.
//
// ws layout (floats): Xa[NXEL], Xb[NXEL], XBLK[NXEL], MT[768*768], PART[512]
// total ~21.2 MB.

#define NXEL 1572864  // 8*256*256*3, invariant across levels

__global__ __launch_bounds__(256) void s2d_kernel(const float* __restrict__ in,
                                                  float* __restrict__ out,
                                                  int H, int C) {
  int W = H;
  int C4 = 4 * C;
  for (int idx = blockIdx.x * 256 + threadIdx.x; idx < NXEL; idx += gridDim.x * 256) {
    int c4 = idx % C4; int rest = idx / C4;
    int w2 = rest % (W >> 1); rest /= (W >> 1);
    int h2 = rest % (H >> 1); int b = rest / (H >> 1);
    int q = c4 / C, c = c4 % C;
    out[idx] = in[(((b * H) + 2 * h2 + (q >> 1)) * W + 2 * w2 + (q & 1)) * C + c];
  }
}

// Mt[k*s+c] = -M[c*s+k]  (negated transpose, so apply loop reads coalesced rows)
__global__ __launch_bounds__(256) void prep_mt_kernel(const float* __restrict__ M,
                                                      float* __restrict__ Mt, int s) {
  int total = s * s;
  for (int idx = blockIdx.x * 256 + threadIdx.x; idx < total; idx += gridDim.x * 256) {
    int k = idx / s, c = idx % s;
    Mt[idx] = -M[c * s + k];
  }
}

// x = expm(-M) (y - eb) via Taylor: acc = v; t = v; for j: t = (A t)/j; acc += t.
// Block: 256 threads, TV=2^tvs threads per vector, NV=256/TV vectors/block,
// each thread owns 6 contiguous components (s = 6*TV for every level).
// T_old lives in LDS (padded stride s+1); Mt in LDS when s<=96, else L2-stream.
template <bool LDSM>
__global__ __launch_bounds__(256) void expm_apply_kernel(
    const float* __restrict__ xin, const float* __restrict__ Mt,
    const float* __restrict__ eb, float* __restrict__ xblk,
    int s, int Cfull, int J, int tvs) {
  extern __shared__ float lds[];
  float* Tb;
  const float* Msrc;
  if (LDSM) {
    float* MtS = lds;
    Tb = lds + s * s;
    for (int i = threadIdx.x; i < s * s; i += 256) MtS[i] = Mt[i];
    Msrc = MtS;
  } else {
    Tb = lds;
    Msrc = Mt;
  }
  int TV = 1 << tvs;
  int v = threadIdx.x >> tvs;
  int p = threadIdx.x & (TV - 1);
  int c0 = p * 6;
  int NV = 256 >> tvs;
  int sp = s + 1;
  long vec = (long)blockIdx.x * NV + v;

  float acc[6];
  const float* xv = xin + vec * Cfull;
#pragma unroll
  for (int m = 0; m < 6; m++) {
    float x = xv[c0 + m] - eb[c0 + m];
    acc[m] = x;
    Tb[v * sp + c0 + m] = x;
  }
  __syncthreads();

  for (int j = 1; j <= J; j++) {
    float inv = 1.0f / (float)j;
    float tn[6] = {0.f, 0.f, 0.f, 0.f, 0.f, 0.f};
    const float* Trow = Tb + v * sp;
    for (int k = 0; k < s; k++) {
      float tv = Trow[k];
      const float* mrow = Msrc + (long)k * s + c0;
#pragma unroll
      for (int m = 0; m < 6; m++) tn[m] = fmaf(mrow[m], tv, tn[m]);
    }
    __syncthreads();
#pragma unroll
    for (int m = 0; m < 6; m++) {
      float t2 = tn[m] * inv;
      acc[m] += t2;
      Tb[v * sp + c0 + m] = t2;
    }
    __syncthreads();
  }

  float* xo = xblk + vec * s;
#pragma unroll
  for (int m = 0; m < 6; m++) xo[c0 + m] = acc[m];
}

// Fused: h = relu(conv3x3_SAME(x0)+cb); shift = h@dw+db; write [x0, x1-shift]
// into xout channels [0,s). Block = TH x TW pixel tile, 256 threads (= out chans).
template <int TH, int TW>
__global__ __launch_bounds__(256) void conv_dense_kernel(
    const float* __restrict__ xblk, float* __restrict__ xout,
    const float* __restrict__ cw, const float* __restrict__ cb,
    const float* __restrict__ dw, const float* __restrict__ db,
    int h, int d, int s, int Cfull) {
  constexpr int P = TH * TW;
  extern __shared__ float lds[];
  float* patch = lds;                              // (TH+2)*(TW+2)*d
  float* hbuf = lds + (TH + 2) * (TW + 2) * d;     // P*257 (padded)
  int w = h;
  int tilesX = w / TW, tilesY = h / TH;
  int bt = blockIdx.x;
  int tx = bt % tilesX; int t1 = bt / tilesX;
  int ty = t1 % tilesY; int b = t1 / tilesY;
  int y0 = ty * TH, x0 = tx * TW;
  int tid = threadIdx.x;

  int patchN = (TH + 2) * (TW + 2) * d;
  for (int idx = tid; idx < patchN; idx += 256) {
    int ci = idx % d; int rest = idx / d;
    int px = rest % (TW + 2); int py = rest / (TW + 2);
    int iy = y0 + py - 1, ix = x0 + px - 1;
    float v = 0.f;
    if (iy >= 0 && iy < h && ix >= 0 && ix < w)
      v = xblk[((long)((b * h + iy) * w + ix)) * s + ci];
    patch[idx] = v;
  }
  __syncthreads();

  float acc[P];
  float cbk = cb[tid];
#pragma unroll
  for (int p = 0; p < P; p++) acc[p] = cbk;
  for (int t = 0; t < 9; t++) {
    int ky = t / 3, kx = t % 3;
    const float* cwt = cw + (long)t * d * 256 + tid;
    const float* pbase = patch + (ky * (TW + 2) + kx) * d;
    for (int ci = 0; ci < d; ci++) {
      float wv = cwt[(long)ci * 256];
#pragma unroll
      for (int p = 0; p < P; p++) {
        int pr = p / TW, pc = p % TW;
        acc[p] = fmaf(pbase[(pr * (TW + 2) + pc) * d + ci], wv, acc[p]);
      }
    }
  }
#pragma unroll
  for (int p = 0; p < P; p++) hbuf[p * 257 + tid] = fmaxf(acc[p], 0.f);
  __syncthreads();

  for (int idx = tid; idx < P * d; idx += 256) {
    int c = idx % d; int p = idx / d;
    float sh = db[c];
    const float* hrow = hbuf + p * 257;
    for (int kk = 0; kk < 256; kk++) sh = fmaf(hrow[kk], dw[(long)kk * d + c], sh);
    int pr = p / TW, pc = p % TW;
    long pix = (long)((b * h + y0 + pr) * w + (x0 + pc));
    float x0v = xblk[pix * s + c];
    float x1v = xblk[pix * s + d + c];
    xout[pix * Cfull + c] = x0v;
    xout[pix * Cfull + d + c] = x1v - sh;
  }
}

__global__ __launch_bounds__(256) void sumsq_kernel(const float* __restrict__ x,
                                                    float* __restrict__ part) {
  __shared__ float red[256];
  int b = blockIdx.x >> 6, ch = blockIdx.x & 63;
  const float* p = x + (long)b * 196608 + ch * 3072;
  float su = 0.f;
  for (int i = threadIdx.x; i < 3072; i += 256) {
    float v = p[i];
    su = fmaf(v, v, su);
  }
  red[threadIdx.x] = su;
  __syncthreads();
  for (int st = 128; st > 0; st >>= 1) {
    if (threadIdx.x < st) red[threadIdx.x] += red[threadIdx.x + st];
    __syncthreads();
  }
  if (threadIdx.x == 0) part[blockIdx.x] = red[0];
}

__global__ __launch_bounds__(256) void finalize_kernel(
    const float* __restrict__ part,
    const float* M1, const float* M2, const float* M3, const float* M4,
    const float* M5, const float* M6, const float* M7, float* __restrict__ out) {
  __shared__ float tr[7];
  int tid = threadIdx.x;
  if (tid < 7) {
    const float* Mp = tid == 0 ? M1 : tid == 1 ? M2 : tid == 2 ? M3 : tid == 3 ? M4
                    : tid == 4 ? M5 : tid == 5 ? M6 : M7;
    int s = 12 << tid;
    float t = 0.f;
    for (int i = 0; i < s; i++) t += Mp[(long)i * s + i];
    tr[tid] = t;
  }
  __syncthreads();
  if (tid < 8) {
    float su = 0.f;
    for (int c = 0; c < 64; c++) su += part[tid * 64 + c];
    float ildj = 0.f;
    const float Hsq[7] = {16384.f, 4096.f, 1024.f, 256.f, 64.f, 16.f, 4.f};
#pragma unroll
    for (int i = 0; i < 7; i++) ildj += expf(tr[i]) * Hsq[i];
    out[tid] = -0.5f * su - 0.5f * 196608.0f * 1.8378770664093453f + ildj;
  }
}

extern "C" void kernel_launch(void* const* d_in, const int* in_sizes, int n_in,
                              void* d_out, int out_size, void* d_ws, size_t ws_size,
                              hipStream_t stream) {
  (void)in_sizes; (void)n_in; (void)out_size;
  const size_t need = ((size_t)3 * NXEL + 768 * 768 + 512) * sizeof(float);
  if (ws_size < need) return;  // fail cleanly (out stays poisoned) rather than corrupt

  const float* sample = (const float*)d_in[0];
  float* ws = (float*)d_ws;
  float* Xa = ws;
  float* Xb = Xa + NXEL;
  float* XBLK = Xb + NXEL;
  float* MT = XBLK + NXEL;
  float* PART = MT + 768 * 768;
  float* out = (float*)d_out;

  // Taylor terms per level; truncation err ||M||^(J+1)/(J+1)! <= ~1e-4 even
  // with 15% norm-overrun margin (||M_i|| ~ 0.1*sqrt(s): 0.35..2.77).
  const int Jarr[7] = {9, 9, 10, 11, 12, 11, 13};

  const float* cur = sample;
  int H = 256, C = 3;
  for (int i = 0; i < 7; i++) {
    int s = 12 << i, d = s >> 1, h = 128 >> i;
    int Cfull = 4 * C;
    int nvec = 8 * h * h;
    int tvs = i + 1;
    int NV = 256 >> tvs;
    bool ldsm = (s <= 96);
    float* xs2d = (i & 1) ? Xb : Xa;
    const float* Mi  = (const float*)d_in[1 + 6 * i + 0];
    const float* ebi = (const float*)d_in[1 + 6 * i + 1];
    const float* cwi = (const float*)d_in[1 + 6 * i + 2];
    const float* cbi = (const float*)d_in[1 + 6 * i + 3];
    const float* dwi = (const float*)d_in[1 + 6 * i + 4];
    const float* dbi = (const float*)d_in[1 + 6 * i + 5];

    s2d_kernel<<<6144, 256, 0, stream>>>(cur, xs2d, H, C);
    prep_mt_kernel<<<(s * s + 255) / 256, 256, 0, stream>>>(Mi, MT, s);

    int ldsB = ((ldsm ? s * s : 0) + NV * (s + 1)) * 4;
    if (ldsm)
      expm_apply_kernel<true><<<nvec / NV, 256, ldsB, stream>>>(
          xs2d, MT, ebi, XBLK, s, Cfull, Jarr[i], tvs);
    else
      expm_apply_kernel<false><<<nvec / NV, 256, ldsB, stream>>>(
          xs2d, MT, ebi, XBLK, s, Cfull, Jarr[i], tvs);

    if (i < 6) {
      int blocks = 8 * (h / 4) * (h / 4);
      int clds = (36 * d + 16 * 257) * 4;
      conv_dense_kernel<4, 4><<<blocks, 256, clds, stream>>>(
          XBLK, xs2d, cwi, cbi, dwi, dbi, h, d, s, Cfull);
    } else {
      int blocks = 8;  // h=2 -> one 2x2 tile per image
      int clds = (16 * d + 4 * 257) * 4;
      conv_dense_kernel<2, 2><<<blocks, 256, clds, stream>>>(
          XBLK, xs2d, cwi, cbi, dwi, dbi, h, d, s, Cfull);
    }
    cur = xs2d;
    H = h;
    C = Cfull;
  }

  sumsq_kernel<<<512, 256, 0, stream>>>(cur, PART);
  finalize_kernel<<<1, 256, 0, stream>>>(
      PART, (const float*)d_in[1], (const float*)d_in[7], (const float*)d_in[13],
      (const float*)d_in[19], (const float*)d_in[25], (const float*)d_in[31],
      (const float*)d_in[37], out);
}

// Round 2
// 2166.327 us; speedup vs baseline: 1.2397x; 1.2397x over previous
//
#include <hip/hip_runtime.h>
#include <hip/hip_bf16.h>
#include <math.h>

// Flow log_prob, fp32 (bf16 only for late-level Mt streaming).
// Per level i (s=12<<i, d=s/2, h=128>>i, Cfull=4*C_prev, nvec=8*h*h):
//   s2d -> expm-apply -> fused conv3x3(d->256)+relu+dense(256->d).
// expm-apply:
//   levels 1-4 (s<=96): single kernel, M in LDS, Taylor chain in-block.
//   levels 5-7 (s>=192): one kernel per Taylor term (grid = out-chunks x nvec),
//     Mt in bf16 (halves the per-CU L2-BW wall that made R1's level-7 631us).
// Then per-batch sum(z^2) + ildj from traces.

#define NXEL 1572864  // 8*256*256*3, invariant across levels

__global__ __launch_bounds__(256) void s2d_kernel(const float* __restrict__ in,
                                                  float* __restrict__ out,
                                                  int H, int C) {
  int W = H;
  int C4 = 4 * C;
  for (int idx = blockIdx.x * 256 + threadIdx.x; idx < NXEL; idx += gridDim.x * 256) {
    int c4 = idx % C4; int rest = idx / C4;
    int w2 = rest % (W >> 1); rest /= (W >> 1);
    int h2 = rest % (H >> 1); int b = rest / (H >> 1);
    int q = c4 / C, c = c4 % C;
    out[idx] = in[(((b * H) + 2 * h2 + (q >> 1)) * W + 2 * w2 + (q & 1)) * C + c];
  }
}

// Mt[k*s+c] = -M[c*s+k]  (negated transpose; apply loops read coalesced rows)
__global__ __launch_bounds__(256) void prep_mt_kernel(const float* __restrict__ M,
                                                      float* __restrict__ Mt, int s) {
  int total = s * s;
  for (int idx = blockIdx.x * 256 + threadIdx.x; idx < total; idx += gridDim.x * 256) {
    int k = idx / s, c = idx % s;
    Mt[idx] = -M[c * s + k];
  }
}

__global__ __launch_bounds__(256) void prep_mt_bf16_kernel(const float* __restrict__ M,
                                                           __hip_bfloat16* __restrict__ Mtb,
                                                           int s) {
  int total = s * s;
  for (int idx = blockIdx.x * 256 + threadIdx.x; idx < total; idx += gridDim.x * 256) {
    int k = idx / s, c = idx % s;
    Mtb[idx] = __float2bfloat16(-M[c * s + k]);
  }
}

// ---- levels 1-4: in-block Taylor chain, M cached in LDS ----
__global__ __launch_bounds__(256) void expm_apply_kernel(
    const float* __restrict__ xin, const float* __restrict__ Mt,
    const float* __restrict__ eb, float* __restrict__ xblk,
    int s, int Cfull, int J, int tvs) {
  extern __shared__ float lds[];
  float* MtS = lds;
  float* Tb = lds + s * s;
  for (int i = threadIdx.x; i < s * s; i += 256) MtS[i] = Mt[i];

  int TV = 1 << tvs;
  int v = threadIdx.x >> tvs;
  int p = threadIdx.x & (TV - 1);
  int c0 = p * 6;
  int NV = 256 >> tvs;
  int sp = s + 1;
  long vec = (long)blockIdx.x * NV + v;

  float acc[6];
  const float* xv = xin + vec * Cfull;
#pragma unroll
  for (int m = 0; m < 6; m++) {
    float x = xv[c0 + m] - eb[c0 + m];
    acc[m] = x;
    Tb[v * sp + c0 + m] = x;
  }
  __syncthreads();

  for (int j = 1; j <= J; j++) {
    float inv = 1.0f / (float)j;
    float tn[6] = {0.f, 0.f, 0.f, 0.f, 0.f, 0.f};
    const float* Trow = Tb + v * sp;
    for (int k = 0; k < s; k++) {
      float tv = Trow[k];
      const float* mrow = MtS + k * s + c0;
#pragma unroll
      for (int m = 0; m < 6; m++) tn[m] = fmaf(mrow[m], tv, tn[m]);
    }
    __syncthreads();
#pragma unroll
    for (int m = 0; m < 6; m++) {
      float t2 = tn[m] * inv;
      acc[m] += t2;
      Tb[v * sp + c0 + m] = t2;
    }
    __syncthreads();
  }

  float* xo = xblk + vec * s;
#pragma unroll
  for (int m = 0; m < 6; m++) xo[c0 + m] = acc[m];
}

// ---- levels 5-7: multi-kernel Taylor; acc lives in XBLK ----
__global__ __launch_bounds__(256) void expm_init_kernel(
    const float* __restrict__ xin, const float* __restrict__ eb,
    float* __restrict__ tcur, float* __restrict__ acc, int s, int Cfull, int nvec) {
  int total = nvec * s;
  for (int idx = blockIdx.x * 256 + threadIdx.x; idx < total; idx += gridDim.x * 256) {
    int c = idx % s; int v = idx / s;
    float x = xin[(long)v * Cfull + c] - eb[c];
    tcur[idx] = x;
    acc[idx] = x;
  }
}

// t_new[v,c] = inv_j * sum_k Mtb[k,c] * t_old[v,k];  acc[v,c] += t_new.
// grid = (ceil(s/256), nvec); t_old row staged in LDS; Mtb read coalesced (bf16).
__global__ __launch_bounds__(256) void taylor_term_kernel(
    const __hip_bfloat16* __restrict__ Mtb, const float* __restrict__ t_old,
    float* __restrict__ t_new, float* __restrict__ acc, int s, float inv_j) {
  extern __shared__ float tv[];  // s floats
  int v = blockIdx.y;
  int c = blockIdx.x * 256 + threadIdx.x;
  const float* trow = t_old + (long)v * s;
  for (int i = threadIdx.x; i < s; i += 256) tv[i] = trow[i];
  __syncthreads();
  if (c < s) {
    float sum = 0.f;
    const __hip_bfloat16* mp = Mtb + c;
#pragma unroll 4
    for (int k = 0; k < s; k++)
      sum = fmaf(__bfloat162float(mp[(long)k * s]), tv[k], sum);
    float tn = sum * inv_j;
    long o = (long)v * s + c;
    t_new[o] = tn;
    acc[o] += tn;
  }
}

// Fused: h = relu(conv3x3_SAME(x0)+cb); shift = h@dw+db; write [x0, x1-shift]
template <int TH, int TW>
__global__ __launch_bounds__(256) void conv_dense_kernel(
    const float* __restrict__ xblk, float* __restrict__ xout,
    const float* __restrict__ cw, const float* __restrict__ cb,
    const float* __restrict__ dw, const float* __restrict__ db,
    int h, int d, int s, int Cfull) {
  constexpr int P = TH * TW;
  extern __shared__ float lds[];
  float* patch = lds;                              // (TH+2)*(TW+2)*d
  float* hbuf = lds + (TH + 2) * (TW + 2) * d;     // P*257 (padded)
  int w = h;
  int tilesX = w / TW, tilesY = h / TH;
  int bt = blockIdx.x;
  int tx = bt % tilesX; int t1 = bt / tilesX;
  int ty = t1 % tilesY; int b = t1 / tilesY;
  int y0 = ty * TH, x0 = tx * TW;
  int tid = threadIdx.x;

  int patchN = (TH + 2) * (TW + 2) * d;
  for (int idx = tid; idx < patchN; idx += 256) {
    int ci = idx % d; int rest = idx / d;
    int px = rest % (TW + 2); int py = rest / (TW + 2);
    int iy = y0 + py - 1, ix = x0 + px - 1;
    float v = 0.f;
    if (iy >= 0 && iy < h && ix >= 0 && ix < w)
      v = xblk[((long)((b * h + iy) * w + ix)) * s + ci];
    patch[idx] = v;
  }
  __syncthreads();

  float acc[P];
  float cbk = cb[tid];
#pragma unroll
  for (int p = 0; p < P; p++) acc[p] = cbk;
  for (int t = 0; t < 9; t++) {
    int ky = t / 3, kx = t % 3;
    const float* cwt = cw + (long)t * d * 256 + tid;
    const float* pbase = patch + (ky * (TW + 2) + kx) * d;
    for (int ci = 0; ci < d; ci++) {
      float wv = cwt[(long)ci * 256];
#pragma unroll
      for (int p = 0; p < P; p++) {
        int pr = p / TW, pc = p % TW;
        acc[p] = fmaf(pbase[(pr * (TW + 2) + pc) * d + ci], wv, acc[p]);
      }
    }
  }
#pragma unroll
  for (int p = 0; p < P; p++) hbuf[p * 257 + tid] = fmaxf(acc[p], 0.f);
  __syncthreads();

  for (int idx = tid; idx < P * d; idx += 256) {
    int c = idx % d; int p = idx / d;
    float sh = db[c];
    const float* hrow = hbuf + p * 257;
    for (int kk = 0; kk < 256; kk++) sh = fmaf(hrow[kk], dw[(long)kk * d + c], sh);
    int pr = p / TW, pc = p % TW;
    long pix = (long)((b * h + y0 + pr) * w + (x0 + pc));
    float x0v = xblk[pix * s + c];
    float x1v = xblk[pix * s + d + c];
    xout[pix * Cfull + c] = x0v;
    xout[pix * Cfull + d + c] = x1v - sh;
  }
}

__global__ __launch_bounds__(256) void sumsq_kernel(const float* __restrict__ x,
                                                    float* __restrict__ part) {
  __shared__ float red[256];
  int b = blockIdx.x >> 6, ch = blockIdx.x & 63;
  const float* p = x + (long)b * 196608 + ch * 3072;
  float su = 0.f;
  for (int i = threadIdx.x; i < 3072; i += 256) {
    float v = p[i];
    su = fmaf(v, v, su);
  }
  red[threadIdx.x] = su;
  __syncthreads();
  for (int st = 128; st > 0; st >>= 1) {
    if (threadIdx.x < st) red[threadIdx.x] += red[threadIdx.x + st];
    __syncthreads();
  }
  if (threadIdx.x == 0) part[blockIdx.x] = red[0];
}

__global__ __launch_bounds__(256) void finalize_kernel(
    const float* __restrict__ part,
    const float* M1, const float* M2, const float* M3, const float* M4,
    const float* M5, const float* M6, const float* M7, float* __restrict__ out) {
  __shared__ float tr[7];
  int tid = threadIdx.x;
  if (tid < 7) {
    const float* Mp = tid == 0 ? M1 : tid == 1 ? M2 : tid == 2 ? M3 : tid == 3 ? M4
                    : tid == 4 ? M5 : tid == 5 ? M6 : M7;
    int s = 12 << tid;
    float t = 0.f;
    for (int i = 0; i < s; i++) t += Mp[(long)i * s + i];
    tr[tid] = t;
  }
  __syncthreads();
  if (tid < 8) {
    float su = 0.f;
    for (int c = 0; c < 64; c++) su += part[tid * 64 + c];
    float ildj = 0.f;
    const float Hsq[7] = {16384.f, 4096.f, 1024.f, 256.f, 64.f, 16.f, 4.f};
#pragma unroll
    for (int i = 0; i < 7; i++) ildj += expf(tr[i]) * Hsq[i];
    out[tid] = -0.5f * su - 0.5f * 196608.0f * 1.8378770664093453f + ildj;
  }
}

extern "C" void kernel_launch(void* const* d_in, const int* in_sizes, int n_in,
                              void* d_out, int out_size, void* d_ws, size_t ws_size,
                              hipStream_t stream) {
  (void)in_sizes; (void)n_in; (void)out_size;
  // ws layout (float slots):
  //   Xa[NXEL] Xb[NXEL] XBLK[NXEL] MT[96*96] MTB(bf16 768^2 -> 294912 slots)
  //   TCUR[98304] TNXT[98304] PART[512]
  const size_t need =
      ((size_t)3 * NXEL + 96 * 96 + 294912 + 2 * 98304 + 512) * sizeof(float);
  if (ws_size < need) return;

  const float* sample = (const float*)d_in[0];
  float* ws = (float*)d_ws;
  float* Xa = ws;
  float* Xb = Xa + NXEL;
  float* XBLK = Xb + NXEL;
  float* MT = XBLK + NXEL;
  __hip_bfloat16* MTB = (__hip_bfloat16*)(MT + 96 * 96);
  float* TCUR = (float*)(MTB + 768 * 768);
  float* TNXT = TCUR + 98304;
  float* PART = TNXT + 98304;
  float* out = (float*)d_out;

  // Taylor terms per level; truncation ||M||^(J+1)/(J+1)! <= ~1e-4
  // (||M_i||_2 ~ 0.1*sqrt(s): 0.35 .. 2.77).
  const int Jarr[7] = {9, 9, 10, 11, 12, 11, 13};

  const float* cur = sample;
  int H = 256, C = 3;
  for (int i = 0; i < 7; i++) {
    int s = 12 << i, d = s >> 1, h = 128 >> i;
    int Cfull = 4 * C;
    int nvec = 8 * h * h;
    float* xs2d = (i & 1) ? Xb : Xa;
    const float* Mi  = (const float*)d_in[1 + 6 * i + 0];
    const float* ebi = (const float*)d_in[1 + 6 * i + 1];
    const float* cwi = (const float*)d_in[1 + 6 * i + 2];
    const float* cbi = (const float*)d_in[1 + 6 * i + 3];
    const float* dwi = (const float*)d_in[1 + 6 * i + 4];
    const float* dbi = (const float*)d_in[1 + 6 * i + 5];

    s2d_kernel<<<6144, 256, 0, stream>>>(cur, xs2d, H, C);

    if (s <= 96) {
      // in-block Taylor, M in LDS
      int tvs = i + 1;
      int NV = 256 >> tvs;
      prep_mt_kernel<<<(s * s + 255) / 256, 256, 0, stream>>>(Mi, MT, s);
      int ldsB = (s * s + NV * (s + 1)) * 4;
      expm_apply_kernel<<<nvec / NV, 256, ldsB, stream>>>(
          xs2d, MT, ebi, XBLK, s, Cfull, Jarr[i], tvs);
    } else {
      // term-per-kernel Taylor, bf16 Mt
      prep_mt_bf16_kernel<<<(s * s + 255) / 256, 256, 0, stream>>>(Mi, MTB, s);
      expm_init_kernel<<<(nvec * s + 255) / 256, 256, 0, stream>>>(
          xs2d, ebi, TCUR, XBLK, s, Cfull, nvec);
      float* ta = TCUR;
      float* tb = TNXT;
      dim3 g((s + 255) / 256, nvec);
      for (int j = 1; j <= Jarr[i]; j++) {
        taylor_term_kernel<<<g, 256, s * 4, stream>>>(MTB, ta, tb, XBLK, s,
                                                      1.0f / (float)j);
        float* tmp = ta; ta = tb; tb = tmp;
      }
    }

    if (i < 6) {
      int blocks = 8 * (h / 4) * (h / 4);
      int clds = (36 * d + 16 * 257) * 4;
      conv_dense_kernel<4, 4><<<blocks, 256, clds, stream>>>(
          XBLK, xs2d, cwi, cbi, dwi, dbi, h, d, s, Cfull);
    } else {
      int blocks = 8;  // h=2 -> one 2x2 tile per image
      int clds = (16 * d + 4 * 257) * 4;
      conv_dense_kernel<2, 2><<<blocks, 256, clds, stream>>>(
          XBLK, xs2d, cwi, cbi, dwi, dbi, h, d, s, Cfull);
    }
    cur = xs2d;
    H = h;
    C = Cfull;
  }

  sumsq_kernel<<<512, 256, 0, stream>>>(cur, PART);
  finalize_kernel<<<1, 256, 0, stream>>>(
      PART, (const float*)d_in[1], (const float*)d_in[7], (const float*)d_in[13],
      (const float*)d_in[19], (const float*)d_in[25], (const float*)d_in[31],
      (const float*)d_in[37], out);
}

// Round 3
// 1424.780 us; speedup vs baseline: 1.8850x; 1.5205x over previous
//
#include <hip/hip_runtime.h>
#include <hip/hip_bf16.h>
#include <math.h>

// Flow log_prob, fp32 (bf16 only for late-level Mt streaming).
// Per level i (s=12<<i, d=s/2, h=128>>i, Cfull=4*C_prev, nvec=8*h*h):
//   s2d -> expm-apply -> conv3x3(d->256)+relu+dense(256->d) coupling.
// expm-apply:
//   levels 1-4 (s<=96): single kernel, M in LDS, Taylor chain in-block.
//   levels 5-7 (s>=192): one kernel per Taylor term, bf16 Mt.
// conv+dense:
//   levels 1-3: fused tile kernel (grid >= 512 blocks, latency OK).
//   levels 4-7: K-split into hbuf_init + conv_part(atomicAdd) + dense_shift
//     (grids ~1024 blocks; fixes R2's 8-block 0.38%-occupancy 400-470us convs).

#define NXEL 1572864  // 8*256*256*3, invariant across levels

__global__ __launch_bounds__(256) void s2d_kernel(const float* __restrict__ in,
                                                  float* __restrict__ out,
                                                  int H, int C) {
  int W = H;
  int C4 = 4 * C;
  for (int idx = blockIdx.x * 256 + threadIdx.x; idx < NXEL; idx += gridDim.x * 256) {
    int c4 = idx % C4; int rest = idx / C4;
    int w2 = rest % (W >> 1); rest /= (W >> 1);
    int h2 = rest % (H >> 1); int b = rest / (H >> 1);
    int q = c4 / C, c = c4 % C;
    out[idx] = in[(((b * H) + 2 * h2 + (q >> 1)) * W + 2 * w2 + (q & 1)) * C + c];
  }
}

// Mt[k*s+c] = -M[c*s+k]  (negated transpose; apply loops read coalesced rows)
__global__ __launch_bounds__(256) void prep_mt_kernel(const float* __restrict__ M,
                                                      float* __restrict__ Mt, int s) {
  int total = s * s;
  for (int idx = blockIdx.x * 256 + threadIdx.x; idx < total; idx += gridDim.x * 256) {
    int k = idx / s, c = idx % s;
    Mt[idx] = -M[c * s + k];
  }
}

__global__ __launch_bounds__(256) void prep_mt_bf16_kernel(const float* __restrict__ M,
                                                           __hip_bfloat16* __restrict__ Mtb,
                                                           int s) {
  int total = s * s;
  for (int idx = blockIdx.x * 256 + threadIdx.x; idx < total; idx += gridDim.x * 256) {
    int k = idx / s, c = idx % s;
    Mtb[idx] = __float2bfloat16(-M[c * s + k]);
  }
}

// ---- levels 1-4: in-block Taylor chain, M cached in LDS ----
__global__ __launch_bounds__(256) void expm_apply_kernel(
    const float* __restrict__ xin, const float* __restrict__ Mt,
    const float* __restrict__ eb, float* __restrict__ xblk,
    int s, int Cfull, int J, int tvs) {
  extern __shared__ float lds[];
  float* MtS = lds;
  float* Tb = lds + s * s;
  for (int i = threadIdx.x; i < s * s; i += 256) MtS[i] = Mt[i];

  int TV = 1 << tvs;
  int v = threadIdx.x >> tvs;
  int p = threadIdx.x & (TV - 1);
  int c0 = p * 6;
  int NV = 256 >> tvs;
  int sp = s + 1;
  long vec = (long)blockIdx.x * NV + v;

  float acc[6];
  const float* xv = xin + vec * Cfull;
#pragma unroll
  for (int m = 0; m < 6; m++) {
    float x = xv[c0 + m] - eb[c0 + m];
    acc[m] = x;
    Tb[v * sp + c0 + m] = x;
  }
  __syncthreads();

  for (int j = 1; j <= J; j++) {
    float inv = 1.0f / (float)j;
    float tn[6] = {0.f, 0.f, 0.f, 0.f, 0.f, 0.f};
    const float* Trow = Tb + v * sp;
    for (int k = 0; k < s; k++) {
      float tv = Trow[k];
      const float* mrow = MtS + k * s + c0;
#pragma unroll
      for (int m = 0; m < 6; m++) tn[m] = fmaf(mrow[m], tv, tn[m]);
    }
    __syncthreads();
#pragma unroll
    for (int m = 0; m < 6; m++) {
      float t2 = tn[m] * inv;
      acc[m] += t2;
      Tb[v * sp + c0 + m] = t2;
    }
    __syncthreads();
  }

  float* xo = xblk + vec * s;
#pragma unroll
  for (int m = 0; m < 6; m++) xo[c0 + m] = acc[m];
}

// ---- levels 5-7: multi-kernel Taylor; acc lives in XBLK ----
__global__ __launch_bounds__(256) void expm_init_kernel(
    const float* __restrict__ xin, const float* __restrict__ eb,
    float* __restrict__ tcur, float* __restrict__ acc, int s, int Cfull, int nvec) {
  int total = nvec * s;
  for (int idx = blockIdx.x * 256 + threadIdx.x; idx < total; idx += gridDim.x * 256) {
    int c = idx % s; int v = idx / s;
    float x = xin[(long)v * Cfull + c] - eb[c];
    tcur[idx] = x;
    acc[idx] = x;
  }
}

// t_new[v,c] = inv_j * sum_k Mtb[k,c] * t_old[v,k];  acc[v,c] += t_new.
__global__ __launch_bounds__(256) void taylor_term_kernel(
    const __hip_bfloat16* __restrict__ Mtb, const float* __restrict__ t_old,
    float* __restrict__ t_new, float* __restrict__ acc, int s, float inv_j) {
  extern __shared__ float tv[];  // s floats
  int v = blockIdx.y;
  int c = blockIdx.x * 256 + threadIdx.x;
  const float* trow = t_old + (long)v * s;
  for (int i = threadIdx.x; i < s; i += 256) tv[i] = trow[i];
  __syncthreads();
  if (c < s) {
    float sum = 0.f;
    const __hip_bfloat16* mp = Mtb + c;
#pragma unroll 4
    for (int k = 0; k < s; k++)
      sum = fmaf(__bfloat162float(mp[(long)k * s]), tv[k], sum);
    float tn = sum * inv_j;
    long o = (long)v * s + c;
    t_new[o] = tn;
    acc[o] += tn;
  }
}

// ---- levels 1-3: fused conv+dense (enough blocks) ----
template <int TH, int TW>
__global__ __launch_bounds__(256) void conv_dense_kernel(
    const float* __restrict__ xblk, float* __restrict__ xout,
    const float* __restrict__ cw, const float* __restrict__ cb,
    const float* __restrict__ dw, const float* __restrict__ db,
    int h, int d, int s, int Cfull) {
  constexpr int P = TH * TW;
  extern __shared__ float lds[];
  float* patch = lds;                              // (TH+2)*(TW+2)*d
  float* hbuf = lds + (TH + 2) * (TW + 2) * d;     // P*257 (padded)
  int w = h;
  int tilesX = w / TW, tilesY = h / TH;
  int bt = blockIdx.x;
  int tx = bt % tilesX; int t1 = bt / tilesX;
  int ty = t1 % tilesY; int b = t1 / tilesY;
  int y0 = ty * TH, x0 = tx * TW;
  int tid = threadIdx.x;

  int patchN = (TH + 2) * (TW + 2) * d;
  for (int idx = tid; idx < patchN; idx += 256) {
    int ci = idx % d; int rest = idx / d;
    int px = rest % (TW + 2); int py = rest / (TW + 2);
    int iy = y0 + py - 1, ix = x0 + px - 1;
    float v = 0.f;
    if (iy >= 0 && iy < h && ix >= 0 && ix < w)
      v = xblk[((long)((b * h + iy) * w + ix)) * s + ci];
    patch[idx] = v;
  }
  __syncthreads();

  float acc[P];
  float cbk = cb[tid];
#pragma unroll
  for (int p = 0; p < P; p++) acc[p] = cbk;
  for (int t = 0; t < 9; t++) {
    int ky = t / 3, kx = t % 3;
    const float* cwt = cw + (long)t * d * 256 + tid;
    const float* pbase = patch + (ky * (TW + 2) + kx) * d;
    for (int ci = 0; ci < d; ci++) {
      float wv = cwt[(long)ci * 256];
#pragma unroll
      for (int p = 0; p < P; p++) {
        int pr = p / TW, pc = p % TW;
        acc[p] = fmaf(pbase[(pr * (TW + 2) + pc) * d + ci], wv, acc[p]);
      }
    }
  }
#pragma unroll
  for (int p = 0; p < P; p++) hbuf[p * 257 + tid] = fmaxf(acc[p], 0.f);
  __syncthreads();

  for (int idx = tid; idx < P * d; idx += 256) {
    int c = idx % d; int p = idx / d;
    float sh = db[c];
    const float* hrow = hbuf + p * 257;
    for (int kk = 0; kk < 256; kk++) sh = fmaf(hrow[kk], dw[(long)kk * d + c], sh);
    int pr = p / TW, pc = p % TW;
    long pix = (long)((b * h + y0 + pr) * w + (x0 + pc));
    float x0v = xblk[pix * s + c];
    float x1v = xblk[pix * s + d + c];
    xout[pix * Cfull + c] = x0v;
    xout[pix * Cfull + d + c] = x1v - sh;
  }
}

// ---- levels 4-7: K-split conv (atomic) + dense ----
__global__ __launch_bounds__(256) void hbuf_init_kernel(float* __restrict__ hbuf,
                                                        const float* __restrict__ cb,
                                                        int nvec) {
  int total = nvec * 256;
  for (int idx = blockIdx.x * 256 + threadIdx.x; idx < total; idx += gridDim.x * 256)
    hbuf[idx] = cb[idx & 255];
}

// grid = (nvec/PIX, KC). Block: stage PIX pixel-patch chunks (LDS), reduce the
// K-chunk [j0,j1) of the 9d conv reduction, atomicAdd 256 partials per pixel.
template <int PIX>
__global__ __launch_bounds__(256) void conv_part_kernel(
    const float* __restrict__ xblk, const float* __restrict__ cw,
    float* __restrict__ hbuf, int h, int d, int s, int chunk) {
  extern __shared__ float pt[];  // PIX * clen
  int w = h;
  int nine_d = 9 * d;
  int j0 = blockIdx.y * chunk;
  int j1 = min(j0 + chunk, nine_d);
  int clen = j1 - j0;
  int pg = blockIdx.x;
  int tid = threadIdx.x;

  for (int idx = tid; idx < PIX * clen; idx += 256) {
    int q = idx / clen, jj = idx % clen;
    int j = j0 + jj;
    int t = j / d, ci = j - t * d;
    int ky = t / 3, kx = t % 3;
    int p = pg * PIX + q;
    int b = p / (h * w); int rem = p - b * h * w;
    int y = rem / w, x = rem - y * w;
    int iy = y + ky - 1, ix = x + kx - 1;
    float v = 0.f;
    if (iy >= 0 && iy < h && ix >= 0 && ix < w)
      v = xblk[((long)((b * h + iy) * w + ix)) * s + ci];
    pt[idx] = v;
  }
  __syncthreads();

  float acc[PIX];
#pragma unroll
  for (int q = 0; q < PIX; q++) acc[q] = 0.f;
  const float* cwp = cw + (long)j0 * 256 + tid;
#pragma unroll 4
  for (int jj = 0; jj < clen; jj++) {
    float cwv = cwp[(long)jj * 256];
#pragma unroll
    for (int q = 0; q < PIX; q++) acc[q] = fmaf(pt[q * clen + jj], cwv, acc[q]);
  }
#pragma unroll
  for (int q = 0; q < PIX; q++)
    atomicAdd(&hbuf[((long)(pg * PIX + q)) * 256 + tid], acc[q]);
}

// shift[p,c] = db[c] + sum_k relu(hbuf[p,k]) dw[k,c]; write [x0, x1-shift]
__global__ __launch_bounds__(256) void dense_shift_kernel(
    const float* __restrict__ xblk, const float* __restrict__ hbuf,
    float* __restrict__ xout, const float* __restrict__ dw,
    const float* __restrict__ db, int d, int s, int Cfull, int total) {
  int gid = blockIdx.x * 256 + threadIdx.x;
  if (gid >= total) return;
  int p = gid / d, c = gid - p * d;
  float sum = db[c];
  const float* hrow = hbuf + (long)p * 256;
#pragma unroll 4
  for (int k = 0; k < 256; k++)
    sum = fmaf(fmaxf(hrow[k], 0.f), dw[(long)k * d + c], sum);
  long pix = p;
  float x0v = xblk[pix * s + c];
  float x1v = xblk[pix * s + d + c];
  xout[pix * Cfull + c] = x0v;
  xout[pix * Cfull + d + c] = x1v - sum;
}

__global__ __launch_bounds__(256) void sumsq_kernel(const float* __restrict__ x,
                                                    float* __restrict__ part) {
  __shared__ float red[256];
  int b = blockIdx.x >> 6, ch = blockIdx.x & 63;
  const float* p = x + (long)b * 196608 + ch * 3072;
  float su = 0.f;
  for (int i = threadIdx.x; i < 3072; i += 256) {
    float v = p[i];
    su = fmaf(v, v, su);
  }
  red[threadIdx.x] = su;
  __syncthreads();
  for (int st = 128; st > 0; st >>= 1) {
    if (threadIdx.x < st) red[threadIdx.x] += red[threadIdx.x + st];
    __syncthreads();
  }
  if (threadIdx.x == 0) part[blockIdx.x] = red[0];
}

__global__ __launch_bounds__(256) void finalize_kernel(
    const float* __restrict__ part,
    const float* M1, const float* M2, const float* M3, const float* M4,
    const float* M5, const float* M6, const float* M7, float* __restrict__ out) {
  __shared__ float tr[7];
  int tid = threadIdx.x;
  if (tid < 7) {
    const float* Mp = tid == 0 ? M1 : tid == 1 ? M2 : tid == 2 ? M3 : tid == 3 ? M4
                    : tid == 4 ? M5 : tid == 5 ? M6 : M7;
    int s = 12 << tid;
    float t = 0.f;
    for (int i = 0; i < s; i++) t += Mp[(long)i * s + i];
    tr[tid] = t;
  }
  __syncthreads();
  if (tid < 8) {
    float su = 0.f;
    for (int c = 0; c < 64; c++) su += part[tid * 64 + c];
    float ildj = 0.f;
    const float Hsq[7] = {16384.f, 4096.f, 1024.f, 256.f, 64.f, 16.f, 4.f};
#pragma unroll
    for (int i = 0; i < 7; i++) ildj += expf(tr[i]) * Hsq[i];
    out[tid] = -0.5f * su - 0.5f * 196608.0f * 1.8378770664093453f + ildj;
  }
}

extern "C" void kernel_launch(void* const* d_in, const int* in_sizes, int n_in,
                              void* d_out, int out_size, void* d_ws, size_t ws_size,
                              hipStream_t stream) {
  (void)in_sizes; (void)n_in; (void)out_size;
  // ws layout (float slots):
  //   Xa[NXEL] Xb[NXEL] XBLK[NXEL] MT[96*96] MTB(bf16 768^2 -> 294912 slots)
  //   TCUR[98304] TNXT[98304] PART[512]
  const size_t need =
      ((size_t)3 * NXEL + 96 * 96 + 294912 + 2 * 98304 + 512) * sizeof(float);
  if (ws_size < need) return;

  const float* sample = (const float*)d_in[0];
  float* ws = (float*)d_ws;
  float* Xa = ws;
  float* Xb = Xa + NXEL;
  float* XBLK = Xb + NXEL;
  float* MT = XBLK + NXEL;
  __hip_bfloat16* MTB = (__hip_bfloat16*)(MT + 96 * 96);
  float* TCUR = (float*)(MTB + 768 * 768);
  float* TNXT = TCUR + 98304;
  float* PART = TNXT + 98304;
  float* out = (float*)d_out;

  // Taylor terms per level; truncation ||M||^(J+1)/(J+1)! <= ~1e-4
  const int Jarr[7] = {9, 9, 10, 11, 12, 11, 13};
  // K-split params for late conv (i>=3): grid = (nvec/PIX) * KC ~ 1024 blocks
  const int PIXa[7] = {0, 0, 0, 8, 8, 4, 2};
  const int KCa[7]  = {0, 0, 0, 4, 16, 32, 64};

  const float* cur = sample;
  int H = 256, C = 3;
  for (int i = 0; i < 7; i++) {
    int s = 12 << i, d = s >> 1, h = 128 >> i;
    int Cfull = 4 * C;
    int nvec = 8 * h * h;
    float* xs2d = (i & 1) ? Xb : Xa;
    float* other = (i & 1) ? Xa : Xb;  // dead after s2d consumes it (i>=1)
    const float* Mi  = (const float*)d_in[1 + 6 * i + 0];
    const float* ebi = (const float*)d_in[1 + 6 * i + 1];
    const float* cwi = (const float*)d_in[1 + 6 * i + 2];
    const float* cbi = (const float*)d_in[1 + 6 * i + 3];
    const float* dwi = (const float*)d_in[1 + 6 * i + 4];
    const float* dbi = (const float*)d_in[1 + 6 * i + 5];

    s2d_kernel<<<6144, 256, 0, stream>>>(cur, xs2d, H, C);

    if (s <= 96) {
      int tvs = i + 1;
      int NV = 256 >> tvs;
      prep_mt_kernel<<<(s * s + 255) / 256, 256, 0, stream>>>(Mi, MT, s);
      int ldsB = (s * s + NV * (s + 1)) * 4;
      expm_apply_kernel<<<nvec / NV, 256, ldsB, stream>>>(
          xs2d, MT, ebi, XBLK, s, Cfull, Jarr[i], tvs);
    } else {
      prep_mt_bf16_kernel<<<(s * s + 255) / 256, 256, 0, stream>>>(Mi, MTB, s);
      expm_init_kernel<<<(nvec * s + 255) / 256, 256, 0, stream>>>(
          xs2d, ebi, TCUR, XBLK, s, Cfull, nvec);
      float* ta = TCUR;
      float* tb = TNXT;
      dim3 g((s + 255) / 256, nvec);
      for (int j = 1; j <= Jarr[i]; j++) {
        taylor_term_kernel<<<g, 256, s * 4, stream>>>(MTB, ta, tb, XBLK, s,
                                                      1.0f / (float)j);
        float* tmp = ta; ta = tb; tb = tmp;
      }
    }

    if (i < 3) {
      int blocks = 8 * (h / 4) * (h / 4);
      int clds = (36 * d + 16 * 257) * 4;
      conv_dense_kernel<4, 4><<<blocks, 256, clds, stream>>>(
          XBLK, xs2d, cwi, cbi, dwi, dbi, h, d, s, Cfull);
    } else {
      // K-split path; HBUF reuses `other` (consumed by s2d already)
      float* HBUF = other;
      int PIX = PIXa[i], KC = KCa[i];
      int nine_d = 9 * d;
      int chunk = (nine_d + KC - 1) / KC;
      hbuf_init_kernel<<<(nvec * 256 + 65535) / 65536 * 256, 256, 0, stream>>>(
          HBUF, cbi, nvec);
      dim3 ga(nvec / PIX, KC);
      int alds = PIX * chunk * 4;
      if (PIX == 8)
        conv_part_kernel<8><<<ga, 256, alds, stream>>>(XBLK, cwi, HBUF, h, d, s, chunk);
      else if (PIX == 4)
        conv_part_kernel<4><<<ga, 256, alds, stream>>>(XBLK, cwi, HBUF, h, d, s, chunk);
      else
        conv_part_kernel<2><<<ga, 256, alds, stream>>>(XBLK, cwi, HBUF, h, d, s, chunk);
      int total = nvec * d;
      dense_shift_kernel<<<(total + 255) / 256, 256, 0, stream>>>(
          XBLK, HBUF, xs2d, dwi, dbi, d, s, Cfull, total);
    }
    cur = xs2d;
    H = h;
    C = Cfull;
  }

  sumsq_kernel<<<512, 256, 0, stream>>>(cur, PART);
  finalize_kernel<<<1, 256, 0, stream>>>(
      PART, (const float*)d_in[1], (const float*)d_in[7], (const float*)d_in[13],
      (const float*)d_in[19], (const float*)d_in[25], (const float*)d_in[31],
      (const float*)d_in[37], out);
}

// Round 4
// 1233.046 us; speedup vs baseline: 2.1781x; 1.1555x over previous
//
#include <hip/hip_runtime.h>
#include <hip/hip_bf16.h>
#include <math.h>

// Flow log_prob, fp32 (bf16 only for late-level Mt streaming).
// Per level i (s=12<<i, d=s/2, h=128>>i, Cfull=4*C_prev, nvec=8*h*h):
//   s2d -> expm-apply -> conv3x3(d->256)+relu+dense(256->d) coupling.
// expm-apply:
//   levels 1-4 (s<=96): single kernel, M in LDS, Taylor chain in-block.
//   levels 5-7 (s>=192): one kernel per Taylor term, bf16 Mt.
// conv+dense:
//   levels 1-3: fused tile kernel (grid >= 512 blocks).
//   levels 4-7: K-split hbuf_init + conv_part(atomicAdd) + dense_shift.
// finalize: traces computed with all 256 threads (R3's 199us was ONE thread
//   serially walking M7's 768-elem diagonal at L2 latency).

#define NXEL 1572864  // 8*256*256*3, invariant across levels

__global__ __launch_bounds__(256) void s2d_kernel(const float* __restrict__ in,
                                                  float* __restrict__ out,
                                                  int H, int C) {
  int W = H;
  int C4 = 4 * C;
  for (int idx = blockIdx.x * 256 + threadIdx.x; idx < NXEL; idx += gridDim.x * 256) {
    int c4 = idx % C4; int rest = idx / C4;
    int w2 = rest % (W >> 1); rest /= (W >> 1);
    int h2 = rest % (H >> 1); int b = rest / (H >> 1);
    int q = c4 / C, c = c4 % C;
    out[idx] = in[(((b * H) + 2 * h2 + (q >> 1)) * W + 2 * w2 + (q & 1)) * C + c];
  }
}

// Mt[k*s+c] = -M[c*s+k]  (negated transpose; apply loops read coalesced rows)
__global__ __launch_bounds__(256) void prep_mt_kernel(const float* __restrict__ M,
                                                      float* __restrict__ Mt, int s) {
  int total = s * s;
  for (int idx = blockIdx.x * 256 + threadIdx.x; idx < total; idx += gridDim.x * 256) {
    int k = idx / s, c = idx % s;
    Mt[idx] = -M[c * s + k];
  }
}

__global__ __launch_bounds__(256) void prep_mt_bf16_kernel(const float* __restrict__ M,
                                                           __hip_bfloat16* __restrict__ Mtb,
                                                           int s) {
  int total = s * s;
  for (int idx = blockIdx.x * 256 + threadIdx.x; idx < total; idx += gridDim.x * 256) {
    int k = idx / s, c = idx % s;
    Mtb[idx] = __float2bfloat16(-M[c * s + k]);
  }
}

// ---- levels 1-4: in-block Taylor chain, M cached in LDS ----
__global__ __launch_bounds__(256) void expm_apply_kernel(
    const float* __restrict__ xin, const float* __restrict__ Mt,
    const float* __restrict__ eb, float* __restrict__ xblk,
    int s, int Cfull, int J, int tvs) {
  extern __shared__ float lds[];
  float* MtS = lds;
  float* Tb = lds + s * s;
  for (int i = threadIdx.x; i < s * s; i += 256) MtS[i] = Mt[i];

  int TV = 1 << tvs;
  int v = threadIdx.x >> tvs;
  int p = threadIdx.x & (TV - 1);
  int c0 = p * 6;
  int NV = 256 >> tvs;
  int sp = s + 1;
  long vec = (long)blockIdx.x * NV + v;

  float acc[6];
  const float* xv = xin + vec * Cfull;
#pragma unroll
  for (int m = 0; m < 6; m++) {
    float x = xv[c0 + m] - eb[c0 + m];
    acc[m] = x;
    Tb[v * sp + c0 + m] = x;
  }
  __syncthreads();

  for (int j = 1; j <= J; j++) {
    float inv = 1.0f / (float)j;
    float tn[6] = {0.f, 0.f, 0.f, 0.f, 0.f, 0.f};
    const float* Trow = Tb + v * sp;
    for (int k = 0; k < s; k++) {
      float tv = Trow[k];
      const float* mrow = MtS + k * s + c0;
#pragma unroll
      for (int m = 0; m < 6; m++) tn[m] = fmaf(mrow[m], tv, tn[m]);
    }
    __syncthreads();
#pragma unroll
    for (int m = 0; m < 6; m++) {
      float t2 = tn[m] * inv;
      acc[m] += t2;
      Tb[v * sp + c0 + m] = t2;
    }
    __syncthreads();
  }

  float* xo = xblk + vec * s;
#pragma unroll
  for (int m = 0; m < 6; m++) xo[c0 + m] = acc[m];
}

// ---- levels 5-7: multi-kernel Taylor; acc lives in XBLK ----
__global__ __launch_bounds__(256) void expm_init_kernel(
    const float* __restrict__ xin, const float* __restrict__ eb,
    float* __restrict__ tcur, float* __restrict__ acc, int s, int Cfull, int nvec) {
  int total = nvec * s;
  for (int idx = blockIdx.x * 256 + threadIdx.x; idx < total; idx += gridDim.x * 256) {
    int c = idx % s; int v = idx / s;
    float x = xin[(long)v * Cfull + c] - eb[c];
    tcur[idx] = x;
    acc[idx] = x;
  }
}

// t_new[v,c] = inv_j * sum_k Mtb[k,c] * t_old[v,k];  acc[v,c] += t_new.
__global__ __launch_bounds__(256) void taylor_term_kernel(
    const __hip_bfloat16* __restrict__ Mtb, const float* __restrict__ t_old,
    float* __restrict__ t_new, float* __restrict__ acc, int s, float inv_j) {
  extern __shared__ float tv[];  // s floats
  int v = blockIdx.y;
  int c = blockIdx.x * 256 + threadIdx.x;
  const float* trow = t_old + (long)v * s;
  for (int i = threadIdx.x; i < s; i += 256) tv[i] = trow[i];
  __syncthreads();
  if (c < s) {
    float sum = 0.f;
    const __hip_bfloat16* mp = Mtb + c;
#pragma unroll 4
    for (int k = 0; k < s; k++)
      sum = fmaf(__bfloat162float(mp[(long)k * s]), tv[k], sum);
    float tn = sum * inv_j;
    long o = (long)v * s + c;
    t_new[o] = tn;
    acc[o] += tn;
  }
}

// ---- levels 1-3: fused conv+dense (enough blocks) ----
template <int TH, int TW>
__global__ __launch_bounds__(256) void conv_dense_kernel(
    const float* __restrict__ xblk, float* __restrict__ xout,
    const float* __restrict__ cw, const float* __restrict__ cb,
    const float* __restrict__ dw, const float* __restrict__ db,
    int h, int d, int s, int Cfull) {
  constexpr int P = TH * TW;
  extern __shared__ float lds[];
  float* patch = lds;                              // (TH+2)*(TW+2)*d
  float* hbuf = lds + (TH + 2) * (TW + 2) * d;     // P*257 (padded)
  int w = h;
  int tilesX = w / TW, tilesY = h / TH;
  int bt = blockIdx.x;
  int tx = bt % tilesX; int t1 = bt / tilesX;
  int ty = t1 % tilesY; int b = t1 / tilesY;
  int y0 = ty * TH, x0 = tx * TW;
  int tid = threadIdx.x;

  int patchN = (TH + 2) * (TW + 2) * d;
  for (int idx = tid; idx < patchN; idx += 256) {
    int ci = idx % d; int rest = idx / d;
    int px = rest % (TW + 2); int py = rest / (TW + 2);
    int iy = y0 + py - 1, ix = x0 + px - 1;
    float v = 0.f;
    if (iy >= 0 && iy < h && ix >= 0 && ix < w)
      v = xblk[((long)((b * h + iy) * w + ix)) * s + ci];
    patch[idx] = v;
  }
  __syncthreads();

  float acc[P];
  float cbk = cb[tid];
#pragma unroll
  for (int p = 0; p < P; p++) acc[p] = cbk;
  for (int t = 0; t < 9; t++) {
    int ky = t / 3, kx = t % 3;
    const float* cwt = cw + (long)t * d * 256 + tid;
    const float* pbase = patch + (ky * (TW + 2) + kx) * d;
    for (int ci = 0; ci < d; ci++) {
      float wv = cwt[(long)ci * 256];
#pragma unroll
      for (int p = 0; p < P; p++) {
        int pr = p / TW, pc = p % TW;
        acc[p] = fmaf(pbase[(pr * (TW + 2) + pc) * d + ci], wv, acc[p]);
      }
    }
  }
#pragma unroll
  for (int p = 0; p < P; p++) hbuf[p * 257 + tid] = fmaxf(acc[p], 0.f);
  __syncthreads();

  for (int idx = tid; idx < P * d; idx += 256) {
    int c = idx % d; int p = idx / d;
    float sh = db[c];
    const float* hrow = hbuf + p * 257;
    for (int kk = 0; kk < 256; kk++) sh = fmaf(hrow[kk], dw[(long)kk * d + c], sh);
    int pr = p / TW, pc = p % TW;
    long pix = (long)((b * h + y0 + pr) * w + (x0 + pc));
    float x0v = xblk[pix * s + c];
    float x1v = xblk[pix * s + d + c];
    xout[pix * Cfull + c] = x0v;
    xout[pix * Cfull + d + c] = x1v - sh;
  }
}

// ---- levels 4-7: K-split conv (atomic) + dense ----
__global__ __launch_bounds__(256) void hbuf_init_kernel(float* __restrict__ hbuf,
                                                        const float* __restrict__ cb,
                                                        int nvec) {
  int total = nvec * 256;
  for (int idx = blockIdx.x * 256 + threadIdx.x; idx < total; idx += gridDim.x * 256)
    hbuf[idx] = cb[idx & 255];
}

// grid = (nvec/PIX, KC). Block: stage PIX pixel-patch chunks (LDS), reduce the
// K-chunk [j0,j1) of the 9d conv reduction, atomicAdd 256 partials per pixel.
template <int PIX>
__global__ __launch_bounds__(256) void conv_part_kernel(
    const float* __restrict__ xblk, const float* __restrict__ cw,
    float* __restrict__ hbuf, int h, int d, int s, int chunk) {
  extern __shared__ float pt[];  // PIX * clen
  int w = h;
  int nine_d = 9 * d;
  int j0 = blockIdx.y * chunk;
  int j1 = min(j0 + chunk, nine_d);
  int clen = j1 - j0;
  int pg = blockIdx.x;
  int tid = threadIdx.x;

  for (int idx = tid; idx < PIX * clen; idx += 256) {
    int q = idx / clen, jj = idx % clen;
    int j = j0 + jj;
    int t = j / d, ci = j - t * d;
    int ky = t / 3, kx = t % 3;
    int p = pg * PIX + q;
    int b = p / (h * w); int rem = p - b * h * w;
    int y = rem / w, x = rem - y * w;
    int iy = y + ky - 1, ix = x + kx - 1;
    float v = 0.f;
    if (iy >= 0 && iy < h && ix >= 0 && ix < w)
      v = xblk[((long)((b * h + iy) * w + ix)) * s + ci];
    pt[idx] = v;
  }
  __syncthreads();

  float acc[PIX];
#pragma unroll
  for (int q = 0; q < PIX; q++) acc[q] = 0.f;
  const float* cwp = cw + (long)j0 * 256 + tid;
#pragma unroll 4
  for (int jj = 0; jj < clen; jj++) {
    float cwv = cwp[(long)jj * 256];
#pragma unroll
    for (int q = 0; q < PIX; q++) acc[q] = fmaf(pt[q * clen + jj], cwv, acc[q]);
  }
#pragma unroll
  for (int q = 0; q < PIX; q++)
    atomicAdd(&hbuf[((long)(pg * PIX + q)) * 256 + tid], acc[q]);
}

// shift[p,c] = db[c] + sum_k relu(hbuf[p,k]) dw[k,c]; write [x0, x1-shift]
__global__ __launch_bounds__(256) void dense_shift_kernel(
    const float* __restrict__ xblk, const float* __restrict__ hbuf,
    float* __restrict__ xout, const float* __restrict__ dw,
    const float* __restrict__ db, int d, int s, int Cfull, int total) {
  int gid = blockIdx.x * 256 + threadIdx.x;
  if (gid >= total) return;
  int p = gid / d, c = gid - p * d;
  float sum = db[c];
  const float* hrow = hbuf + (long)p * 256;
#pragma unroll 4
  for (int k = 0; k < 256; k++)
    sum = fmaf(fmaxf(hrow[k], 0.f), dw[(long)k * d + c], sum);
  long pix = p;
  float x0v = xblk[pix * s + c];
  float x1v = xblk[pix * s + d + c];
  xout[pix * Cfull + c] = x0v;
  xout[pix * Cfull + d + c] = x1v - sum;
}

__global__ __launch_bounds__(256) void sumsq_kernel(const float* __restrict__ x,
                                                    float* __restrict__ part) {
  __shared__ float red[256];
  int b = blockIdx.x >> 6, ch = blockIdx.x & 63;
  const float* p = x + (long)b * 196608 + ch * 3072;
  float su = 0.f;
  for (int i = threadIdx.x; i < 3072; i += 256) {
    float v = p[i];
    su = fmaf(v, v, su);
  }
  red[threadIdx.x] = su;
  __syncthreads();
  for (int st = 128; st > 0; st >>= 1) {
    if (threadIdx.x < st) red[threadIdx.x] += red[threadIdx.x + st];
    __syncthreads();
  }
  if (threadIdx.x == 0) part[blockIdx.x] = red[0];
}

__global__ __launch_bounds__(256) void finalize_kernel(
    const float* __restrict__ part,
    const float* M1, const float* M2, const float* M3, const float* M4,
    const float* M5, const float* M6, const float* M7, float* __restrict__ out) {
  __shared__ float red[256];
  __shared__ float tr[7];
  int tid = threadIdx.x;
  // Parallel per-level trace: 256 threads stride the diagonal, LDS reduce.
  for (int i = 0; i < 7; i++) {
    const float* Mp = i == 0 ? M1 : i == 1 ? M2 : i == 2 ? M3 : i == 3 ? M4
                    : i == 4 ? M5 : i == 5 ? M6 : M7;
    int s = 12 << i;
    float su = 0.f;
    for (int idx = tid; idx < s; idx += 256) su += Mp[(long)idx * s + idx];
    red[tid] = su;
    __syncthreads();
    for (int st = 128; st > 0; st >>= 1) {
      if (tid < st) red[tid] += red[tid + st];
      __syncthreads();
    }
    if (tid == 0) tr[i] = red[0];
    __syncthreads();
  }
  if (tid < 8) {
    float su = 0.f;
    for (int c = 0; c < 64; c++) su += part[tid * 64 + c];
    float ildj = 0.f;
    const float Hsq[7] = {16384.f, 4096.f, 1024.f, 256.f, 64.f, 16.f, 4.f};
#pragma unroll
    for (int i = 0; i < 7; i++) ildj += expf(tr[i]) * Hsq[i];
    out[tid] = -0.5f * su - 0.5f * 196608.0f * 1.8378770664093453f + ildj;
  }
}

extern "C" void kernel_launch(void* const* d_in, const int* in_sizes, int n_in,
                              void* d_out, int out_size, void* d_ws, size_t ws_size,
                              hipStream_t stream) {
  (void)in_sizes; (void)n_in; (void)out_size;
  // ws layout (float slots):
  //   Xa[NXEL] Xb[NXEL] XBLK[NXEL] MT[96*96] MTB(bf16 768^2 -> 294912 slots)
  //   TCUR[98304] TNXT[98304] PART[512]
  const size_t need =
      ((size_t)3 * NXEL + 96 * 96 + 294912 + 2 * 98304 + 512) * sizeof(float);
  if (ws_size < need) return;

  const float* sample = (const float*)d_in[0];
  float* ws = (float*)d_ws;
  float* Xa = ws;
  float* Xb = Xa + NXEL;
  float* XBLK = Xb + NXEL;
  float* MT = XBLK + NXEL;
  __hip_bfloat16* MTB = (__hip_bfloat16*)(MT + 96 * 96);
  float* TCUR = (float*)(MTB + 768 * 768);
  float* TNXT = TCUR + 98304;
  float* PART = TNXT + 98304;
  float* out = (float*)d_out;

  // Taylor terms per level; truncation ||M||^(J+1)/(J+1)! <= ~1e-4
  const int Jarr[7] = {9, 9, 10, 11, 12, 11, 13};
  // K-split params for late conv (i>=3): grid = (nvec/PIX) * KC ~ 1024 blocks
  const int PIXa[7] = {0, 0, 0, 8, 8, 4, 2};
  const int KCa[7]  = {0, 0, 0, 4, 16, 32, 64};

  const float* cur = sample;
  int H = 256, C = 3;
  for (int i = 0; i < 7; i++) {
    int s = 12 << i, d = s >> 1, h = 128 >> i;
    int Cfull = 4 * C;
    int nvec = 8 * h * h;
    float* xs2d = (i & 1) ? Xb : Xa;
    float* other = (i & 1) ? Xa : Xb;  // dead after s2d consumes it (i>=1)
    const float* Mi  = (const float*)d_in[1 + 6 * i + 0];
    const float* ebi = (const float*)d_in[1 + 6 * i + 1];
    const float* cwi = (const float*)d_in[1 + 6 * i + 2];
    const float* cbi = (const float*)d_in[1 + 6 * i + 3];
    const float* dwi = (const float*)d_in[1 + 6 * i + 4];
    const float* dbi = (const float*)d_in[1 + 6 * i + 5];

    s2d_kernel<<<6144, 256, 0, stream>>>(cur, xs2d, H, C);

    if (s <= 96) {
      int tvs = i + 1;
      int NV = 256 >> tvs;
      prep_mt_kernel<<<(s * s + 255) / 256, 256, 0, stream>>>(Mi, MT, s);
      int ldsB = (s * s + NV * (s + 1)) * 4;
      expm_apply_kernel<<<nvec / NV, 256, ldsB, stream>>>(
          xs2d, MT, ebi, XBLK, s, Cfull, Jarr[i], tvs);
    } else {
      prep_mt_bf16_kernel<<<(s * s + 255) / 256, 256, 0, stream>>>(Mi, MTB, s);
      expm_init_kernel<<<(nvec * s + 255) / 256, 256, 0, stream>>>(
          xs2d, ebi, TCUR, XBLK, s, Cfull, nvec);
      float* ta = TCUR;
      float* tb = TNXT;
      dim3 g((s + 255) / 256, nvec);
      for (int j = 1; j <= Jarr[i]; j++) {
        taylor_term_kernel<<<g, 256, s * 4, stream>>>(MTB, ta, tb, XBLK, s,
                                                      1.0f / (float)j);
        float* tmp = ta; ta = tb; tb = tmp;
      }
    }

    if (i < 3) {
      int blocks = 8 * (h / 4) * (h / 4);
      int clds = (36 * d + 16 * 257) * 4;
      conv_dense_kernel<4, 4><<<blocks, 256, clds, stream>>>(
          XBLK, xs2d, cwi, cbi, dwi, dbi, h, d, s, Cfull);
    } else {
      // K-split path; HBUF reuses `other` (consumed by s2d already)
      float* HBUF = other;
      int PIX = PIXa[i], KC = KCa[i];
      int nine_d = 9 * d;
      int chunk = (nine_d + KC - 1) / KC;
      hbuf_init_kernel<<<(nvec * 256 + 65535) / 65536 * 256, 256, 0, stream>>>(
          HBUF, cbi, nvec);
      dim3 ga(nvec / PIX, KC);
      int alds = PIX * chunk * 4;
      if (PIX == 8)
        conv_part_kernel<8><<<ga, 256, alds, stream>>>(XBLK, cwi, HBUF, h, d, s, chunk);
      else if (PIX == 4)
        conv_part_kernel<4><<<ga, 256, alds, stream>>>(XBLK, cwi, HBUF, h, d, s, chunk);
      else
        conv_part_kernel<2><<<ga, 256, alds, stream>>>(XBLK, cwi, HBUF, h, d, s, chunk);
      int total = nvec * d;
      dense_shift_kernel<<<(total + 255) / 256, 256, 0, stream>>>(
          XBLK, HBUF, xs2d, dwi, dbi, d, s, Cfull, total);
    }
    cur = xs2d;
    H = h;
    C = Cfull;
  }

  sumsq_kernel<<<512, 256, 0, stream>>>(cur, PART);
  finalize_kernel<<<1, 256, 0, stream>>>(
      PART, (const float*)d_in[1], (const float*)d_in[7], (const float*)d_in[13],
      (const float*)d_in[19], (const float*)d_in[25], (const float*)d_in[31],
      (const float*)d_in[37], out);
}